// Round 18
// baseline (5123.252 us; speedup 1.0000x reference)
//
#include <hip/hip_runtime.h>
#include <math.h>

#define NB 16
#define NC 512
#define NH 38
#define NW 50
#define NHW 1900          // 38*50
#define NPOS 30400        // 16*1900
#define NANCH 17100       // 1900*9
#define PRE_N 6000
#define POST_N 300
#define NWORD 96          // ceil(6000/64)=94, ROUNDED UP to the 4-word tile
                          // (r17 bug: NWORD=94 let tile bj=23 write 2 words
                          //  into the next row -> corrupted suppression bits)
#define KTOT 4608         // 512*9
#define NIT 576           // KTOT/8
#define IMGH 608.0f
#define IMGW 800.0f

typedef unsigned long long u64;

// ---------------------------------------------------------------------------
// Kernel 1: 3x3 conv (verified r16): 128co x 128pos, BK=8, 8x8 f64 acc,
// straight LDS, double-buffered, 1 barrier/iter. Bitwise-identical
// activations (serial k-order 0..4607). Grid (15, 4, 16), block 256.
// ---------------------------------------------------------------------------
__global__ __launch_bounds__(256, 2)
void conv_f64_v8(const float* __restrict__ x, const float* __restrict__ w,
                 const float* __restrict__ bias, float* __restrict__ out)
{
    const int b    = blockIdx.z;
    const int co0  = blockIdx.y * 128;
    const int pos0 = blockIdx.x * 128;

    __shared__ __align__(16) double Ad[2][8][130];   // [buf][k][co]
    __shared__ __align__(16) double Bd[2][8][128];   // [buf][k][pos] (straight)

    const int tid = threadIdx.x;
    const int ty  = tid >> 4;
    const int tx  = tid & 15;

    double acc[8][8];
#pragma unroll
    for (int m = 0; m < 8; ++m)
#pragma unroll
        for (int n = 0; n < 8; ++n) acc[m][n] = 0.0;

    const float* xb = x + (size_t)b * NC * NHW;

    const int coiA = tid >> 1;
    const int k4A  = (tid & 1) * 4;
    const float* wptr = w + (size_t)(co0 + coiA) * KTOT + k4A;

    const int kkB = tid >> 5;
    const int piB = tid & 31;
    int  pyj[4], pxj[4];
    bool okj[4];
#pragma unroll
    for (int j = 0; j < 4; ++j) {
        const int p = pos0 + piB + j * 32;
        const int py = p / NW;
        pyj[j] = py;
        pxj[j] = p - py * NW;
        okj[j] = p < NHW;
    }

    int ky = kkB / 3;
    int kx = kkB - 3 * (kkB / 3);
    const float* xci = xb;

    float4 wa;
    float  bs[4];

#define LOAD_B()                                                              \
    {                                                                         \
        _Pragma("unroll")                                                     \
        for (int j = 0; j < 4; ++j) {                                         \
            const int yy = pyj[j] + ky - 1;                                   \
            const int xx = pxj[j] + kx - 1;                                   \
            bs[j] = (okj[j] && (unsigned)yy < (unsigned)NH &&                 \
                     (unsigned)xx < (unsigned)NW) ? xci[yy * NW + xx] : 0.f;  \
        }                                                                     \
    }

#define ADV_STATE()                                                           \
    {                                                                         \
        const bool wrap = (ky == 0) && (kx == 0);                             \
        if (wrap) { ky = 2; kx = 2; }                                         \
        else {                                                                \
            --kx;                                                             \
            if (kx < 0) { kx = 2; --ky; }                                     \
            xci += NHW;                                                       \
        }                                                                     \
    }

#define STAGE(buf)                                                            \
    {                                                                         \
        Ad[buf][k4A + 0][coiA] = (double)wa.x;                                \
        Ad[buf][k4A + 1][coiA] = (double)wa.y;                                \
        Ad[buf][k4A + 2][coiA] = (double)wa.z;                                \
        Ad[buf][k4A + 3][coiA] = (double)wa.w;                                \
        _Pragma("unroll")                                                     \
        for (int j = 0; j < 4; ++j) Bd[buf][kkB][piB + j * 32] = (double)bs[j];\
    }

    wa = *reinterpret_cast<const float4*>(wptr);
    LOAD_B();
    ADV_STATE();
    STAGE(0);
    __syncthreads();

    int cur = 0;
    for (int it = 0; it < NIT; ++it) {
        const bool more = (it + 1) < NIT;
        if (more) {
            wptr += 8;
            wa = *reinterpret_cast<const float4*>(wptr);
            LOAD_B();
            ADV_STATE();
        }

#pragma unroll
        for (int kk = 0; kk < 8; ++kk) {
            double av[8], bv[8];
#pragma unroll
            for (int m = 0; m < 8; ++m) av[m] = Ad[cur][kk][ty * 8 + m];
#pragma unroll
            for (int n = 0; n < 8; ++n) bv[n] = Bd[cur][kk][n * 16 + tx];
#pragma unroll
            for (int m = 0; m < 8; ++m)
#pragma unroll
                for (int n = 0; n < 8; ++n) acc[m][n] += av[m] * bv[n];
        }

        if (more) {
            const int nb = cur ^ 1;
            STAGE(nb);
            __syncthreads();
        }
        cur ^= 1;
    }
#undef LOAD_B
#undef ADV_STATE
#undef STAGE

#pragma unroll
    for (int m = 0; m < 8; ++m) {
        const int co = co0 + ty * 8 + m;
        const double bi = (double)bias[co];
        float* orow = out + ((size_t)b * NC + co) * NHW;
#pragma unroll
        for (int n = 0; n < 8; ++n) {
            const int pos = pos0 + n * 16 + tx;
            if (pos < NHW) {
                const double d = acc[m][n] + bi;
                orow[pos] = (float)(d > 0.0 ? d : 0.0);
            }
        }
    }
}

// ---------------------------------------------------------------------------
// Kernel 2a: head partial (verified r15): 6-way output split; bitwise-
// identical f32 logits/locs. Grid (119, 6), block 256.
// ---------------------------------------------------------------------------
__global__ __launch_bounds__(256)
void head_part(const float* __restrict__ act,
               const float* __restrict__ cls_w, const float* __restrict__ cls_b,
               const float* __restrict__ reg_w, const float* __restrict__ reg_b,
               float* __restrict__ hl)
{
    const int p = blockIdx.x * 256 + threadIdx.x;
    if (p >= NPOS) return;
    const int g  = blockIdx.y;
    const int b  = p / NHW;
    const int hw = p - b * NHW;

    const float* av = act + (size_t)b * NC * NHW + hw;

    const float* wrow[9];
    double bia[9];
#pragma unroll
    for (int j = 0; j < 9; ++j) {
        const int o = g * 9 + j;
        if (o < 18) { wrow[j] = cls_w + (size_t)o * NC;        bia[j] = (double)cls_b[o]; }
        else        { wrow[j] = reg_w + (size_t)(o - 18) * NC; bia[j] = (double)reg_b[o - 18]; }
    }

    double acc[9];
#pragma unroll
    for (int j = 0; j < 9; ++j) acc[j] = 0.0;

    for (int c = 0; c < NC; ++c) {
        const double v = (double)av[(size_t)c * NHW];
#pragma unroll
        for (int j = 0; j < 9; ++j) acc[j] += v * (double)wrow[j][c];
    }

    float* hb = hl + (size_t)b * 54 * NHW + hw;
#pragma unroll
    for (int j = 0; j < 9; ++j)
        hb[(size_t)(g * 9 + j) * NHW] = (float)(acc[j] + bia[j]);
}

// ---------------------------------------------------------------------------
// Kernel 2b: decode (verified r15, byte-identical).
// ---------------------------------------------------------------------------
__global__ __launch_bounds__(256)
void decode_k(const float* __restrict__ hl,
              float* __restrict__ boxes, float* __restrict__ scores)
{
    const int p = blockIdx.x * 256 + threadIdx.x;
    if (p >= NPOS) return;
    const int b  = p / NHW;
    const int hw = p - b * NHW;

    const float* hb = hl + (size_t)b * 54 * NHW + hw;

    float lg[18];
#pragma unroll
    for (int o = 0; o < 18; ++o) lg[o] = hb[(size_t)o * NHW];
    float loc[36];
#pragma unroll
    for (int o = 0; o < 36; ++o) loc[o] = hb[(size_t)(18 + o) * NHW];

    double mx = -1e300;
#pragma unroll
    for (int o = 0; o < 18; ++o) mx = fmax(mx, (double)lg[o]);
    double sum = 0.0;
#pragma unroll
    for (int o = 0; o < 18; ++o) sum += exp((double)lg[o] - mx);
    const double inv = 1.0 / sum;

    const int hy = hw / NW;
    const int hx = hw - hy * NW;
    const float shy = (float)(hy * 16);
    const float shx = (float)(hx * 16);

    const double rats[3] = {0.5, 1.0, 2.0};
    const double scls[3] = {8.0, 16.0, 32.0};

#pragma unroll
    for (int a = 0; a < 9; ++a) {
        const int ir = a / 3, is = a - ir * 3;
        const double hh = 16.0 * scls[is] * sqrt(rats[ir]);
        const double wd = 16.0 * scls[is] * sqrt(1.0 / rats[ir]);
        const float ay1 = (float)(8.0 - hh * 0.5) + shy;
        const float ax1 = (float)(8.0 - wd * 0.5) + shx;
        const float ay2 = (float)(8.0 + hh * 0.5) + shy;
        const float ax2 = (float)(8.0 + wd * 0.5) + shx;
        const float ahf = ay2 - ay1;
        const float awf = ax2 - ax1;
        const float acy = ay1 + 0.5f * ahf;
        const float acx = ax1 + 0.5f * awf;

        const double ah = (double)ahf, aw = (double)awf;
        const double dy = (double)loc[4 * a + 0];
        const double dx = (double)loc[4 * a + 1];
        const double dh = (double)loc[4 * a + 2];
        const double dw = (double)loc[4 * a + 3];
        const double cy = dy * ah + (double)acy;
        const double cx = dx * aw + (double)acx;
        const double bh = exp(dh) * ah;
        const double bw = exp(dw) * aw;
        float y1 = (float)(cy - 0.5 * bh);
        float x1 = (float)(cx - 0.5 * bw);
        float y2 = (float)(cy + 0.5 * bh);
        float x2 = (float)(cx + 0.5 * bw);
        y1 = fminf(fmaxf(y1, 0.f), IMGH);
        y2 = fminf(fmaxf(y2, 0.f), IMGH);
        x1 = fminf(fmaxf(x1, 0.f), IMGW);
        x2 = fminf(fmaxf(x2, 0.f), IMGW);
        const bool keep = ((y2 - y1) >= 16.0f) && ((x2 - x1) >= 16.0f);

        float sc = (float)(exp((double)lg[2 * a + 1] - mx) * inv);
        if (!keep) sc = -INFINITY;

        const int n = hw * 9 + a;
        float4 bx; bx.x = y1; bx.y = x1; bx.z = y2; bx.w = x2;
        *reinterpret_cast<float4*>(&boxes[((size_t)b * NANCH + n) * 4]) = bx;
        scores[(size_t)b * NANCH + n] = sc;
    }
}

// ---------------------------------------------------------------------------
// Kernel 3: exact rank sort (verified r4, byte-identical).
// ---------------------------------------------------------------------------
__global__ __launch_bounds__(256)
void rank2(const float* __restrict__ scores, const float* __restrict__ boxes,
           float* __restrict__ sortedS, float* __restrict__ sortedB)
{
    const int b = blockIdx.y;
    const int i = blockIdx.x * 256 + threadIdx.x;
    if (i >= NANCH) return;
    const float si = scores[(size_t)b * NANCH + i];
    const float* sb = scores + (size_t)b * NANCH;
    int rank = 0;
    for (int j = 0; j < NANCH; ++j) {
        const float sj = sb[j];
        rank += (sj > si) || (sj == si && j < i);
    }
    if (rank < PRE_N) {
        sortedS[(size_t)b * PRE_N + rank] = si;
        const float4 bx = *reinterpret_cast<const float4*>(&boxes[((size_t)b * NANCH + i) * 4]);
        *reinterpret_cast<float4*>(&sortedB[((size_t)b * PRE_N + rank) * 4]) = bx;
    }
}

// ---------------------------------------------------------------------------
// Kernel 4a: NMS suppression bitmask. mask[b][i][w] bit (j&63) of word
// w=j>>6 says "i suppresses j" (j>i, IoU>0.7). Float expressions identical
// to the proven nms3 (fmaxf clips, aj+ai-inter+1e-9f, >0.7f). Tiles
// 256 i x 256 j; boxes LDS-staged. Grid (24, 24, 16), block 256; row stride
// NWORD=96 words so tile bj=23 (words 92..95) stays in-bounds.
// ---------------------------------------------------------------------------
__global__ __launch_bounds__(256)
void nms_mask(const float* __restrict__ sortedB, u64* __restrict__ msk)
{
    const int bi = blockIdx.x;
    const int bj = blockIdx.y;
    if (bj < bi) return;
    const int b  = blockIdx.z;
    const int ti = threadIdx.x;

    __shared__ __align__(16) float jb[256][4];

    const float* BB = sortedB + (size_t)b * PRE_N * 4;

    // stage the 256 j-boxes (clamped load; bits for j>=PRE_N are masked off)
    {
        const int j = bj * 256 + ti;
        const int jc = j < PRE_N ? j : 0;
        const float4 bx = *reinterpret_cast<const float4*>(&BB[(size_t)jc * 4]);
        jb[ti][0] = bx.x; jb[ti][1] = bx.y; jb[ti][2] = bx.z; jb[ti][3] = bx.w;
    }
    __syncthreads();

    const int i = bi * 256 + ti;
    if (i >= PRE_N) return;
    const float4 ib = *reinterpret_cast<const float4*>(&BB[(size_t)i * 4]);
    const float ai = fmaxf(ib.z - ib.x, 0.f) * fmaxf(ib.w - ib.y, 0.f);

    u64* row = msk + ((size_t)b * PRE_N + i) * NWORD + bj * 4;
#pragma unroll
    for (int wdi = 0; wdi < 4; ++wdi) {
        u64 bits = 0;
        for (int jj = 0; jj < 64; ++jj) {
            const int lidx = wdi * 64 + jj;
            const int j = bj * 256 + lidx;
            const float jy1 = jb[lidx][0], jx1 = jb[lidx][1];
            const float jy2 = jb[lidx][2], jx2 = jb[lidx][3];
            const float aj  = fmaxf(jy2 - jy1, 0.f) * fmaxf(jx2 - jx1, 0.f);
            const float yy1 = fmaxf(jy1, ib.x);
            const float xx1 = fmaxf(jx1, ib.y);
            const float yy2 = fminf(jy2, ib.z);
            const float xx2 = fminf(jx2, ib.w);
            const float inter = fmaxf(yy2 - yy1, 0.f) * fmaxf(xx2 - xx1, 0.f);
            const float iou = inter / (aj + ai - inter + 1e-9f);
            if ((iou > 0.7f) && (j > i) && (j < PRE_N))
                bits |= (1ull << jj);
        }
        row[wdi] = bits;
    }
}

// ---------------------------------------------------------------------------
// Kernel 4b: greedy scan over the bitmask — exactly the greedy NMS (candidate
// kept iff no earlier-kept suppresses it; ≡ nms3 ≡ nms2 ≡ reference, proven
// r7/r8). One wave per image; 64-candidate batched eligibility via ballot.
// ---------------------------------------------------------------------------
__global__ __launch_bounds__(64)
void nms_scan(const float* __restrict__ sortedS, const float* __restrict__ sortedB,
              const u64* __restrict__ msk, float* __restrict__ out)
{
    const int b    = blockIdx.x;
    const int lane = threadIdx.x;

    __shared__ u64 removed[NWORD];
    __shared__ int keepIdx[POST_N];

    for (int wdi = lane; wdi < NWORD; wdi += 64) removed[wdi] = 0;
    __syncthreads();

    const float* SS = sortedS + (size_t)b * PRE_N;
    const float* BB = sortedB + (size_t)b * PRE_N * 4;
    const u64* MB   = msk + (size_t)b * PRE_N * NWORD;

    int nk = 0;
    int c  = 0;
    while (c < PRE_N && nk < POST_N) {
        const int myc = c + lane;
        bool fin = false, sup = true;
        if (myc < PRE_N) {
            const float s = SS[myc];
            fin = (s != -INFINITY);
            const u64 wv = removed[myc >> 6];
            sup = (wv >> (myc & 63)) & 1ull;
        }
        const u64 elig   = __ballot(fin && !sup);
        const u64 anyinf = __ballot(myc < PRE_N && !fin);
        if (elig == 0ull) {
            if (anyinf != 0ull) break;   // sorted desc: no finite remain
            c += 64;
            continue;
        }
        const int k = c + (int)__builtin_ctzll(elig);
        if (lane == 0) keepIdx[nk] = k;
        ++nk;
        const u64* row = MB + (size_t)k * NWORD;
        for (int wdi = lane; wdi < NWORD; wdi += 64) removed[wdi] |= row[wdi];
        __syncthreads();
        c = k + 1;
    }
    __syncthreads();

    for (int t = lane; t < POST_N; t += 64) {
        float o0 = 0.f, o1 = 0.f, o2 = 0.f, o3 = 0.f, o4 = 0.f;
        if (t < nk) {
            const int k = keepIdx[t];
            const float4 bx = *reinterpret_cast<const float4*>(&BB[(size_t)k * 4]);
            o0 = bx.x; o1 = bx.y; o2 = bx.z; o3 = bx.w; o4 = SS[k];
        }
        float* orow = out + ((size_t)b * POST_N + t) * 5;
        orow[0] = o0; orow[1] = o1; orow[2] = o2; orow[3] = o3; orow[4] = o4;
    }
}

// ---------------------------------------------------------------------------
static const float* pick_input(void* const* d_in, const int* in_sizes, int n_in,
                               int want, int fallback)
{
    for (int i = 0; i < n_in; ++i)
        if (in_sizes[i] == want) return (const float*)d_in[i];
    return (const float*)d_in[fallback];
}

extern "C" void kernel_launch(void* const* d_in, const int* in_sizes, int n_in,
                              void* d_out, int out_size, void* d_ws, size_t ws_size,
                              hipStream_t stream)
{
    const float* x       = pick_input(d_in, in_sizes, n_in, 15564800, 0);
    const float* share_w = pick_input(d_in, in_sizes, n_in, 2359296, 1);
    const float* share_b = pick_input(d_in, in_sizes, n_in, 512, 2);
    const float* cls_w   = pick_input(d_in, in_sizes, n_in, 9216, 3);
    const float* cls_b   = pick_input(d_in, in_sizes, n_in, 18, 4);
    const float* reg_w   = pick_input(d_in, in_sizes, n_in, 18432, 5);
    const float* reg_b   = pick_input(d_in, in_sizes, n_in, 36, 6);
    float* out = (float*)d_out;

    // workspace layout (floats); total 20,280,000 = 81.1 MB (132 MB proven r7).
    // mask (18,432,000 floats) overlaps act+hl (both dead once rank2 has run;
    // memset is stream-ordered after rank2).
    float* W = (float*)d_ws;
    float* sortedB = W;                   // 16*6000*4  =    384,000
    float* sortedS = W + 384000;          // 16*6000    =     96,000
    u64*   msk     = (u64*)(W + 480000);  // 16*6000*96 u64 = 18,432,000 floats
    float* act     = W + 480000;          // 15,564,800  (inside mask region)
    float* hl      = W + 16044800;        //  1,641,600  (inside mask region)
    float* boxes   = W + 18912000;        //  1,094,400
    float* scores  = W + 20006400;        //    273,600

    conv_f64_v8<<<dim3(15, 4, NB), 256, 0, stream>>>(x, share_w, share_b, act);

    head_part<<<dim3(119, 6), 256, 0, stream>>>(act, cls_w, cls_b,
                                                reg_w, reg_b, hl);

    decode_k<<<dim3(119), 256, 0, stream>>>(hl, boxes, scores);

    rank2<<<dim3(67, 16), 256, 0, stream>>>(scores, boxes, sortedS, sortedB);

    hipMemsetAsync(msk, 0, (size_t)NB * PRE_N * NWORD * sizeof(u64), stream);

    nms_mask<<<dim3(24, 24, NB), 256, 0, stream>>>(sortedB, msk);

    nms_scan<<<dim3(NB), 64, 0, stream>>>(sortedS, sortedB, msk, out);
}